// Round 8
// baseline (180.881 us; speedup 1.0000x reference)
//
#include <hip/hip_runtime.h>

typedef __attribute__((ext_vector_type(8))) short s16x8;
typedef __attribute__((ext_vector_type(4))) float f32x4;
typedef __attribute__((ext_vector_type(2))) float f32x2;
typedef __attribute__((ext_vector_type(2))) __bf16 bf16x2;
typedef unsigned short u16;
typedef unsigned int   u32;

#define MFMA16(a,b,c) __builtin_amdgcn_mfma_f32_16x16x32_bf16((a),(b),(c),0,0,0)

__device__ __forceinline__ float bf2f(u16 u){
  u32 x = ((u32)u) << 16; float f; __builtin_memcpy(&f, &x, 4); return f;
}
__device__ __forceinline__ float bflo(u32 v){   // low bf16 of packed pair
  u32 x = v << 16; float f; __builtin_memcpy(&f, &x, 4); return f;
}
__device__ __forceinline__ float bfhi(u32 v){   // high bf16 of packed pair
  u32 x = v & 0xFFFF0000u; float f; __builtin_memcpy(&f, &x, 4); return f;
}
__device__ __forceinline__ u16 f2bf(float f){
  u32 x; __builtin_memcpy(&x, &f, 4);
  x += 0x7FFFu + ((x >> 16) & 1u);   // round-to-nearest-even
  return (u16)(x >> 16);
}
// pack two f32 -> packed bf16 pair (a in low 16, b in high 16), RNE.
// gfx950: clang lowers __bf16 casts to the native convert; this is the
// sanctioned fast path (round 2: gat 117->94us from this alone).
__device__ __forceinline__ u32 pack2(float a, float b){
  bf16x2 h = { (__bf16)a, (__bf16)b };
  return __builtin_bit_cast(u32, h);
}
#if defined(__has_builtin) && __has_builtin(__builtin_amdgcn_exp2f)
__device__ __forceinline__ float fexp2(float x){ return __builtin_amdgcn_exp2f(x); }
#else
extern "C" __device__ float __ocml_native_exp2_f32(float);
__device__ __forceinline__ float fexp2(float x){ return __ocml_native_exp2_f32(x); }
#endif

// Layouts:
// xf_swz : [mtile=1024][kc=22][lane=64][8]  A[m=lane&15][k=kc*32+(lane>>4)*8+j]
// w1_swz : [ntile=16]  [kc=22][lane=64][8]  B[k=...][n=ntile*16+(lane&15)]
// wp[l*4+h] : [32 rows o][stride 40 f];
//   rows 0..25 : 0.25 * W^T          (0.25 head-mean folded in — exact, pow2)
//   row  26    : log2e * (W @ a_src)  row 27 : log2e * (W @ a_dst)
//   rows 28..31 / cols >= 26 : 0
// gat LDS (pad-32 nodes, WAVE-PRIVATE per local batch w):
//   xs [128 rows = w*32+n][stride 32]; hsT[28 rows o][stride 136] SINGLE-HEAD.
//   Head pipeline (round 7): all DS reads of head h (sdv/si/am -> regs) are
//   issued BEFORE matmul1(h+1) runs; same-wave LDS ops execute in order, so
//   the single-head buffer stays correct while the h+1 writes are issued
//   behind the h reads. Read latency hides under matmul1(h+1) MFMAs+packs;
//   softmax(h) then runs from registers. Zero barriers in the layer loop.
//   Register-budget history: (256,8) cap 64 -> heavy spill (r4, hbm 5x);
//   (256,6) cap 84 -> mild spill (r5). (256,5) cap ~102 + reg diet (lazy sdv
//   unpack, late am loads) -> clean (r6: WRITE_SIZE 22528). Pipeline adds
//   ~22 live regs across matmul1(h+1); tripwire WRITE_SIZE > 25K = spill.
// ---------------------------------------------------------------------------
// prep: blocks 0..351: W1 -> w1_swz; blocks 352..363: wp for lh = blk-352.
// ---------------------------------------------------------------------------
__global__ __launch_bounds__(256) void prep_kernel(
    const float* __restrict__ W, const float* __restrict__ a_src,
    const float* __restrict__ a_dst, const float* __restrict__ W1,
    u16* __restrict__ w1t, u16* __restrict__ wp)
{
  const int t = threadIdx.x;
  if (blockIdx.x < 352){
    const int k = blockIdx.x * 2;            // 0..702 even
    const int n = t;
    float v0 = 0.f, v1 = 0.f;
    if (k < 676)     v0 = W1[(size_t)k*256 + n];
    if (k + 1 < 676) v1 = W1[(size_t)(k+1)*256 + n];
    const int ntile = n >> 4, lm = n & 15;
    const int kc = k >> 5, q16 = (k >> 3) & 3, j = k & 7;
    u16* dst = w1t + ((((size_t)ntile*22 + kc)*64 + q16*16 + lm) << 3) + j;
    *(u32*)dst = pack2(v0, v1);
  } else {
    const int lh = blockIdx.x - 352;         // 0..11 = l*4+h
    const float* Wlh = W + lh*676;           // [f][o]
    u16* dst = wp + lh*32*40;
    for (int e = t; e < 1280; e += 256) dst[e] = 0;
    __syncthreads();
    for (int e = t; e < 676; e += 256){      // value rows: 0.25*W^T
      int f = e/26, o = e%26;
      dst[o*40 + f] = f2bf(0.25f * Wlh[f*26 + o]);
    }
    if (t < 52){                             // score rows: log2e * (W@a)
      int sel = t/26, f = t%26;
      const float* av = (sel ? a_dst : a_src) + lh*26;
      float acc = 0.f;
      #pragma unroll
      for (int o = 0; o < 26; ++o) acc += Wlh[f*26 + o]*av[o];
      dst[(26 + sel)*40 + f] = f2bf(1.4426950408889634f * acc);
    }
  }
}

// ---------------------------------------------------------------------------
// GAT kernel: 3 fused layers, barrier-free layer loop (wave = batch for both
// matmuls; xs/hsT regions wave-private). One block = 4 batches, 256 threads,
// ~5 blocks/CU. Head-pipelined: reads(h) -> matmul1(h+1) -> softmax+PV(h).
// Single __syncthreads before the xf tail store.
// ---------------------------------------------------------------------------
__global__ __launch_bounds__(256, 5) void gat_kernel(
    const float* __restrict__ x, const u16* __restrict__ wp,
    u16* __restrict__ xf)
{
  __shared__ __align__(16) u16 xs [128*32];
  __shared__ __align__(16) u16 hsT[28*136];

  const int tid  = threadIdx.x;
  const int w    = tid >> 6;                 // wave = local batch
  const int lane = tid & 63;
  const int q    = lane >> 4;
  const int lm   = lane & 15;
  const int lmc  = (lm < 11) ? lm : 11;      // clamp for am1 row reads
  const int b0   = blockIdx.x * 4;
  const int b32  = w*32;
  const float L2E = 1.4426950408889634f;

  // poison masks for d11 (o = 16+lm = 27, node col 16+q*4+r >= 26)
  const bool pm01 = (lm == 11) && (q == 3);  // regs 0,1
  const bool pm23 = (lm == 11) && (q >= 2);  // regs 2,3

  // wave-private xs zero (own 32 rows = 512 u32), then stage own batch
  for (int e = lane; e < 512; e += 64) ((u32*)xs)[w*512 + e] = 0;
  for (int pp = lane; pp < 338; pp += 64){
    int n = pp/13, p = pp%13;
    float2 v = *(const float2*)&x[(size_t)(b0 + w)*676 + n*26 + 2*p];
    *(u32*)&xs[((b32 + n) << 5) + 2*p] = pack2(v.x, v.y);
  }

  for (int l = 0; l < 3; ++l){
    s16x8 af0 = *(const s16x8*)&xs[((b32      + lm) << 5) + q*8];
    s16x8 af1 = *(const s16x8*)&xs[((b32 + 16 + lm) << 5) + q*8];
    f32x4 acc00 = {0,0,0,0}, acc01 = acc00, acc10 = acc00, acc11 = acc00;
    const int j0 = q*8;

    // matmul1 for one head: h_aug = x @ W_aug -> hsT (wave-private slice)
    auto mfma1_head = [&](int h){
      s16x8 bfr0 = *(const s16x8*)&wp[((l*4 + h)*32      + lm)*40 + q*8];
      s16x8 bfr1 = *(const s16x8*)&wp[((l*4 + h)*32 + 16 + lm)*40 + q*8];
      f32x4 z = {0.f,0.f,0.f,0.f};
      f32x4 d00 = MFMA16(af0, bfr0, z);   // nodes 0..15,  o = lm
      f32x4 d10 = MFMA16(af1, bfr0, z);   // nodes 16..31, o = lm
      f32x4 d01 = MFMA16(af0, bfr1, z);   // nodes 0..15,  o = 16+lm
      f32x4 d11 = MFMA16(af1, bfr1, z);   // nodes 16..31, o = 16+lm
      // poison s_dst (o=27) pad node cols >= 26
      d11[0] = pm01 ? -1e30f : d11[0];
      d11[1] = pm01 ? -1e30f : d11[1];
      d11[2] = pm23 ? -1e30f : d11[2];
      d11[3] = pm23 ? -1e30f : d11[3];
      const int rlo = lm*136 + b32 + q*4;
      { uint2 uu; uu.x = pack2(d00[0], d00[1]); uu.y = pack2(d00[2], d00[3]);
        *(uint2*)&hsT[rlo] = uu; }
      { uint2 uu; uu.x = pack2(d10[0], d10[1]); uu.y = pack2(d10[2], d10[3]);
        *(uint2*)&hsT[rlo + 16] = uu; }
      if (lm < 12){
        const int rhi = (16 + lm)*136 + b32 + q*4;
        { uint2 uu; uu.x = pack2(d01[0], d01[1]); uu.y = pack2(d01[2], d01[3]);
          *(uint2*)&hsT[rhi] = uu; }
        { uint2 uu; uu.x = pack2(d11[0], d11[1]); uu.y = pack2(d11[2], d11[3]);
          *(uint2*)&hsT[rhi + 16] = uu; }
      }
    };

    mfma1_head(0);
    #pragma unroll
    for (int h = 0; h < 4; ++h){
      // ---- early DS reads of head h -> registers (before h+1 writes) ----
      uint4 sdv = *(const uint4*)&hsT[27*136 + b32 + j0];
      f32x2 si;                    // .x -> i = lm (nt=0), .y -> i = 16+lm
      si.x = bf2f(hsT[26*136 + b32 + lm]);
      si.y = bf2f(hsT[26*136 + b32 + 16 + lm]);
      s16x8 am0 = *(const s16x8*)&hsT[ lm      *136 + b32 + j0];
      s16x8 am1 = *(const s16x8*)&hsT[(16+lmc)*136 + b32 + j0];

      // ---- overlap: matmul1 of next head (hides the read latency) ----
      if (h < 3) mfma1_head(h+1);

      // ---- softmax(h) in-register (row-paired), PV accumulate ----
      f32x2 p2[8]; f32x2 loc = {0.f, 0.f};
      #pragma unroll
      for (int jj = 0; jj < 8; ++jj){
        // lazy unpack (constant-folded per unrolled jj)
        u32 word = (jj < 2) ? sdv.x : (jj < 4) ? sdv.y
                 : (jj < 6) ? sdv.z : sdv.w;
        float sdj = (jj & 1) ? bfhi(word) : bflo(word);
        f32x2 e  = si + sdj;                   // v_pk_add_f32
        f32x2 e2 = e * 0.2f;                   // v_pk_mul_f32
        f32x2 m;                               // leaky (log2 domain)
        m.x = fmaxf(e.x, e2.x);
        m.y = fmaxf(e.y, e2.y);
        f32x2 pv;
        pv.x = fexp2(m.x);                     // pad cols: exp2(-1e30)=0
        pv.y = fexp2(m.y);
        p2[jj] = pv;
        loc += pv;                             // v_pk_add_f32
      }
      float t0 = loc.x, t1 = loc.y;
      t0 += __shfl_xor(t0, 16); t0 += __shfl_xor(t0, 32);
      t1 += __shfl_xor(t1, 16); t1 += __shfl_xor(t1, 32);
      f32x2 rinv;
      rinv.x = __builtin_amdgcn_rcpf(t0);
      rinv.y = __builtin_amdgcn_rcpf(t1);
      #pragma unroll
      for (int jj = 0; jj < 8; ++jj) p2[jj] *= rinv;  // v_pk_mul_f32
      uint4 bu0 = { pack2(p2[0].x, p2[1].x), pack2(p2[2].x, p2[3].x),
                    pack2(p2[4].x, p2[5].x), pack2(p2[6].x, p2[7].x) };
      uint4 bu1 = { pack2(p2[0].y, p2[1].y), pack2(p2[2].y, p2[3].y),
                    pack2(p2[4].y, p2[5].y), pack2(p2[6].y, p2[7].y) };
      s16x8 bf0 = __builtin_bit_cast(s16x8, bu0);
      s16x8 bf1 = __builtin_bit_cast(s16x8, bu1);
      acc00 = MFMA16(am0, bf0, acc00);
      acc10 = MFMA16(am1, bf0, acc10);
      acc01 = MFMA16(am0, bf1, acc01);
      acc11 = MFMA16(am1, bf1, acc11);
    }
    // epilogue: heads pre-meaned (0.25 in wp), ELU, write next-layer xs
    #pragma unroll
    for (int nt = 0; nt < 2; ++nt){
      int i = nt*16 + lm;
      if (i < 26){
        int rowb = (b32 + i) << 5;
        #pragma unroll
        for (int mt = 0; mt < 2; ++mt){
          f32x4 a = (mt == 0) ? (nt == 0 ? acc00 : acc01)
                              : (nt == 0 ? acc10 : acc11);
          int f0 = mt*16 + q*4;
          float v0 = a[0], v1 = a[1], v2 = a[2], v3 = a[3];
          v0 = (v0 > 0.f) ? v0 : (fexp2(v0*L2E) - 1.f);
          v1 = (v1 > 0.f) ? v1 : (fexp2(v1*L2E) - 1.f);
          v2 = (v2 > 0.f) ? v2 : (fexp2(v2*L2E) - 1.f);
          v3 = (v3 > 0.f) ? v3 : (fexp2(v3*L2E) - 1.f);
          if (f0 <= 20){
            uint2 uu; uu.x = pack2(v0, v1); uu.y = pack2(v2, v3);
            *(uint2*)&xs[rowb + f0] = uu;
          } else if (f0 == 24){
            *(u32*)&xs[rowb + 24] = pack2(v0, v1);
          }
        }
      }
    }
    // no barrier: xs rows b32.. are wave-private
  }
  __syncthreads();   // tail store mixes batches within 64B chunks
  // store x_final into swizzled A-fragment layout, destination-linear:
  // each 16-thread group writes one contiguous 64B chunk (4 rows x 8 bf16).
  {
    const int mtile = b0 >> 4;
    const int lrow0 = b0 & 15;               // 0,4,8,12
    u16* dstb = xf + (size_t)mtile*22*64*8;
    for (int e = tid; e < 1408; e += 256){
      int chunk = e >> 4;                    // 0..87 = kc*4 + q16
      int u     = e & 15;                    // u32 slot within 64B chunk
      int kc = chunk >> 2, q16 = chunk & 3;
      int bb = u >> 2;                       // local batch 0..3
      int j2 = (u & 3) * 2;
      int k  = kc*32 + q16*8 + j2;           // flat feature (0..703, even)
      u32 v = 0;
      if (k < 676){ int n = k/26, f = k - n*26; v = *(const u32*)&xs[((bb*32 + n) << 5) + f]; }
      *(u32*)&dstb[((kc*64 + q16*16 + lrow0 + bb) << 3) + j2] = v;
    }
  }
}

// ---------------------------------------------------------------------------
// MLP: out = leaky(xf @ W1 + b1, 0.2) @ W2 + b2.  BM=32, grid 512 (2/CU,
// 8 waves/CU). Barrier-free, LDS-free K-loop with 2-stage register prefetch;
// all fragments coalesced (1KB/wave) from swizzled layouts. Fused W2 head.
// ---------------------------------------------------------------------------
__global__ __launch_bounds__(256, 2) void mlp_kernel(
    const u16* __restrict__ xf, const u16* __restrict__ w1t,
    const float* __restrict__ b1, const float* __restrict__ w2,
    const float* __restrict__ b2, float* __restrict__ out)
{
  __shared__ float b1s[256];
  __shared__ float w2s[256*3];
  __shared__ float part[4*32*3];

  const int tid  = threadIdx.x;
  const int w    = tid >> 6;
  const int lane = tid & 63;
  const int q    = lane >> 4;
  const int lm   = lane & 15;
  const int m0   = blockIdx.x * 32;
  const int mt0  = blockIdx.x * 2;         // 2 mtiles per block

  b1s[tid] = b1[tid];
  for (int e = tid; e < 768; e += 256) w2s[e] = w2[e];

  f32x4 acc[2][4];
  #pragma unroll
  for (int a = 0; a < 2; ++a)
    #pragma unroll
    for (int b = 0; b < 4; ++b) acc[a][b] = (f32x4){0.f,0.f,0.f,0.f};

  const u16* abase = xf  + ((size_t)mt0*22*64 + lane) * 8;
  const u16* bbase = w1t + (((size_t)w*4)*22*64 + lane) * 8;

  s16x8 af[2], bf[4], afn[2], bfn[4];
  #pragma unroll
  for (int mt = 0; mt < 2; ++mt) af[mt] = *(const s16x8*)(abase + (size_t)(mt*22)*64*8);
  #pragma unroll
  for (int nt = 0; nt < 4; ++nt) bf[nt] = *(const s16x8*)(bbase + (size_t)(nt*22)*64*8);

  #pragma unroll
  for (int kc = 0; kc < 22; ++kc){
    if (kc < 21){
      #pragma unroll
      for (int mt = 0; mt < 2; ++mt)
        afn[mt] = *(const s16x8*)(abase + (size_t)(mt*22 + kc + 1)*64*8);
      #pragma unroll
      for (int nt = 0; nt < 4; ++nt)
        bfn[nt] = *(const s16x8*)(bbase + (size_t)(nt*22 + kc + 1)*64*8);
    }
    #pragma unroll
    for (int mt = 0; mt < 2; ++mt)
      #pragma unroll
      for (int nt = 0; nt < 4; ++nt)
        acc[mt][nt] = MFMA16(af[mt], bf[nt], acc[mt][nt]);
    #pragma unroll
    for (int mt = 0; mt < 2; ++mt) af[mt] = afn[mt];
    #pragma unroll
    for (int nt = 0; nt < 4; ++nt) bf[nt] = bfn[nt];
  }

  // epilogue: +b1, leaky, @W2 partials, reduce over 16 lanes (cols)
  float b1l[4], w2l[4][3];
  #pragma unroll
  for (int nt = 0; nt < 4; ++nt){
    int col = w*64 + nt*16 + lm;
    b1l[nt] = b1s[col];
    w2l[nt][0] = w2s[col*3]; w2l[nt][1] = w2s[col*3+1]; w2l[nt][2] = w2s[col*3+2];
  }
  float po[2][4][3];
  #pragma unroll
  for (int mt = 0; mt < 2; ++mt)
    #pragma unroll
    for (int r = 0; r < 4; ++r){
      float s0 = 0.f, s1 = 0.f, s2 = 0.f;
      #pragma unroll
      for (int nt = 0; nt < 4; ++nt){
        float hv = acc[mt][nt][r] + b1l[nt];
        hv = (hv >= 0.f) ? hv : 0.2f*hv;
        s0 += hv*w2l[nt][0]; s1 += hv*w2l[nt][1]; s2 += hv*w2l[nt][2];
      }
      po[mt][r][0] = s0; po[mt][r][1] = s1; po[mt][r][2] = s2;
    }
  #pragma unroll
  for (int m = 1; m < 16; m <<= 1)
    #pragma unroll
    for (int mt = 0; mt < 2; ++mt)
      #pragma unroll
      for (int r = 0; r < 4; ++r)
        #pragma unroll
        for (int kk = 0; kk < 3; ++kk)
          po[mt][r][kk] += __shfl_xor(po[mt][r][kk], m);
  if (lm == 0){
    #pragma unroll
    for (int mt = 0; mt < 2; ++mt)
      #pragma unroll
      for (int r = 0; r < 4; ++r)
        #pragma unroll
        for (int kk = 0; kk < 3; ++kk)
          part[w*96 + (mt*16 + q*4 + r)*3 + kk] = po[mt][r][kk];
  }
  __syncthreads();
  if (tid < 96){
    int row = tid/3, kk = tid - row*3;
    float o = part[row*3 + kk] + part[96 + row*3 + kk]
            + part[192 + row*3 + kk] + part[288 + row*3 + kk] + b2[kk];
    out[(m0 + row)*3 + kk] = o;
  }
}

extern "C" void kernel_launch(void* const* d_in, const int* in_sizes, int n_in,
                              void* d_out, int out_size, void* d_ws, size_t ws_size,
                              hipStream_t stream)
{
  (void)in_sizes; (void)n_in; (void)out_size; (void)ws_size;
  const float* x     = (const float*)d_in[1];
  const float* W     = (const float*)d_in[2];
  const float* a_src = (const float*)d_in[3];
  const float* a_dst = (const float*)d_in[4];
  const float* W1    = (const float*)d_in[5];
  const float* b1    = (const float*)d_in[6];
  const float* W2    = (const float*)d_in[7];
  const float* b2    = (const float*)d_in[8];
  float* out = (float*)d_out;

  u16* xfinal = (u16*)d_ws;                    // [1024][22][64][8] bf16 (swz)
  u16* w1t    = xfinal + (size_t)16384*704;    // [16][22][64][8]   bf16 (swz)
  u16* wp     = w1t    + 256*704;              // [12][32][40]      bf16

  hipLaunchKernelGGL(prep_kernel, dim3(364),  dim3(256), 0, stream,
                     W, a_src, a_dst, W1, w1t, wp);
  hipLaunchKernelGGL(gat_kernel,  dim3(4096), dim3(256), 0, stream, x, wp, xfinal);
  hipLaunchKernelGGL(mlp_kernel,  dim3(512),  dim3(256), 0, stream,
                     xfinal, w1t, b1, W2, b2, out);
}

// Round 9
// 179.169 us; speedup vs baseline: 1.0096x; 1.0096x over previous
//
#include <hip/hip_runtime.h>

typedef __attribute__((ext_vector_type(8))) short s16x8;
typedef __attribute__((ext_vector_type(4))) float f32x4;
typedef __attribute__((ext_vector_type(2))) float f32x2;
typedef __attribute__((ext_vector_type(2))) __bf16 bf16x2;
typedef unsigned short u16;
typedef unsigned int   u32;

#define MFMA16(a,b,c) __builtin_amdgcn_mfma_f32_16x16x32_bf16((a),(b),(c),0,0,0)

__device__ __forceinline__ float bf2f(u16 u){
  u32 x = ((u32)u) << 16; float f; __builtin_memcpy(&f, &x, 4); return f;
}
__device__ __forceinline__ float bflo(u32 v){   // low bf16 of packed pair
  u32 x = v << 16; float f; __builtin_memcpy(&f, &x, 4); return f;
}
__device__ __forceinline__ float bfhi(u32 v){   // high bf16 of packed pair
  u32 x = v & 0xFFFF0000u; float f; __builtin_memcpy(&f, &x, 4); return f;
}
__device__ __forceinline__ u16 f2bf(float f){
  u32 x; __builtin_memcpy(&x, &f, 4);
  x += 0x7FFFu + ((x >> 16) & 1u);   // round-to-nearest-even
  return (u16)(x >> 16);
}
// pack two f32 -> packed bf16 pair (a in low 16, b in high 16), RNE.
// gfx950: clang lowers __bf16 casts to the native convert; this is the
// sanctioned fast path (round 2: gat 117->94us from this alone).
__device__ __forceinline__ u32 pack2(float a, float b){
  bf16x2 h = { (__bf16)a, (__bf16)b };
  return __builtin_bit_cast(u32, h);
}
#if defined(__has_builtin) && __has_builtin(__builtin_amdgcn_exp2f)
__device__ __forceinline__ float fexp2(float x){ return __builtin_amdgcn_exp2f(x); }
#else
extern "C" __device__ float __ocml_native_exp2_f32(float);
__device__ __forceinline__ float fexp2(float x){ return __ocml_native_exp2_f32(x); }
#endif

// Layouts:
// xf_swz : [mtile=1024][kc=22][lane=64][8]  A[m=lane&15][k=kc*32+(lane>>4)*8+j]
// w1_swz : [ntile=16]  [kc=22][lane=64][8]  B[k=...][n=ntile*16+(lane&15)]
// wp[l*4+h] : [32 rows o][stride 40 f];
//   rows 0..25 : 0.25 * W^T          (0.25 head-mean folded in — exact, pow2)
//   row  26    : log2e * (W @ a_src)  row 27 : log2e * (W @ a_dst)
//   rows 28..31 / cols >= 26 : 0
// gat LDS (pad-32 nodes, WAVE-PRIVATE per local batch w):
//   xs [128 rows = w*32+n][stride 32]; hsT[28 rows o][stride 136] SINGLE-HEAD
//   (heads interleaved matmul1(h) -> matmul2(h); wave-private, zero barriers).
//   Register/occupancy history (the controlling resource):
//     (256,8) cap 64  -> heavy spill (r4: hbm_bytes 5x, gat 110us)
//     (256,6) cap 84, no diet -> mild spill (r5: WRITE +13MB, gat 85)
//     (256,5) cap 102 + diet  -> clean, VGPR 40, occ 53.7%, gat 82.8 (r6)
//     r7 early-read pipeline: +8 VGPR, occ 45.6%, gat 84.7 -> REVERTED.
//   This round: diet + (256,6): live set ~80 should fit the 84 cap ->
//   6 waves/SIMD. Tripwire: WRITE_SIZE > 25K = spill -> revert to (256,5).
// ---------------------------------------------------------------------------
// prep: blocks 0..351: W1 -> w1_swz; blocks 352..363: wp for lh = blk-352.
// ---------------------------------------------------------------------------
__global__ __launch_bounds__(256) void prep_kernel(
    const float* __restrict__ W, const float* __restrict__ a_src,
    const float* __restrict__ a_dst, const float* __restrict__ W1,
    u16* __restrict__ w1t, u16* __restrict__ wp)
{
  const int t = threadIdx.x;
  if (blockIdx.x < 352){
    const int k = blockIdx.x * 2;            // 0..702 even
    const int n = t;
    float v0 = 0.f, v1 = 0.f;
    if (k < 676)     v0 = W1[(size_t)k*256 + n];
    if (k + 1 < 676) v1 = W1[(size_t)(k+1)*256 + n];
    const int ntile = n >> 4, lm = n & 15;
    const int kc = k >> 5, q16 = (k >> 3) & 3, j = k & 7;
    u16* dst = w1t + ((((size_t)ntile*22 + kc)*64 + q16*16 + lm) << 3) + j;
    *(u32*)dst = pack2(v0, v1);
  } else {
    const int lh = blockIdx.x - 352;         // 0..11 = l*4+h
    const float* Wlh = W + lh*676;           // [f][o]
    u16* dst = wp + lh*32*40;
    for (int e = t; e < 1280; e += 256) dst[e] = 0;
    __syncthreads();
    for (int e = t; e < 676; e += 256){      // value rows: 0.25*W^T
      int f = e/26, o = e%26;
      dst[o*40 + f] = f2bf(0.25f * Wlh[f*26 + o]);
    }
    if (t < 52){                             // score rows: log2e * (W@a)
      int sel = t/26, f = t%26;
      const float* av = (sel ? a_dst : a_src) + lh*26;
      float acc = 0.f;
      #pragma unroll
      for (int o = 0; o < 26; ++o) acc += Wlh[f*26 + o]*av[o];
      dst[(26 + sel)*40 + f] = f2bf(1.4426950408889634f * acc);
    }
  }
}

// ---------------------------------------------------------------------------
// GAT kernel: 3 fused layers, barrier-free layer loop (wave = batch for both
// matmuls; xs/hsT regions wave-private). One block = 4 batches, 256 threads,
// target 6 blocks/CU. Heads interleaved per-layer: matmul1(h) -> hsT ->
// softmax+PV(h); write->read hazard is wave-local lgkmcnt, hidden by
// multi-wave occupancy. Single __syncthreads before the xf tail store.
// ---------------------------------------------------------------------------
__global__ __launch_bounds__(256, 6) void gat_kernel(
    const float* __restrict__ x, const u16* __restrict__ wp,
    u16* __restrict__ xf)
{
  __shared__ __align__(16) u16 xs [128*32];
  __shared__ __align__(16) u16 hsT[28*136];

  const int tid  = threadIdx.x;
  const int w    = tid >> 6;                 // wave = local batch
  const int lane = tid & 63;
  const int q    = lane >> 4;
  const int lm   = lane & 15;
  const int lmc  = (lm < 11) ? lm : 11;      // clamp for am1 row reads
  const int b0   = blockIdx.x * 4;
  const int b32  = w*32;
  const float L2E = 1.4426950408889634f;

  // poison masks for d11 (o = 16+lm = 27, node col 16+q*4+r >= 26)
  const bool pm01 = (lm == 11) && (q == 3);  // regs 0,1
  const bool pm23 = (lm == 11) && (q >= 2);  // regs 2,3

  // wave-private xs zero (own 32 rows = 512 u32), then stage own batch
  for (int e = lane; e < 512; e += 64) ((u32*)xs)[w*512 + e] = 0;
  for (int pp = lane; pp < 338; pp += 64){
    int n = pp/13, p = pp%13;
    float2 v = *(const float2*)&x[(size_t)(b0 + w)*676 + n*26 + 2*p];
    *(u32*)&xs[((b32 + n) << 5) + 2*p] = pack2(v.x, v.y);
  }

  for (int l = 0; l < 3; ++l){
    s16x8 af0 = *(const s16x8*)&xs[((b32      + lm) << 5) + q*8];
    s16x8 af1 = *(const s16x8*)&xs[((b32 + 16 + lm) << 5) + q*8];
    f32x4 acc00 = {0,0,0,0}, acc01 = acc00, acc10 = acc00, acc11 = acc00;
    const int j0 = q*8;
    #pragma unroll
    for (int h = 0; h < 4; ++h){
      // ---- matmul1(h): h_aug = x @ W_aug -> hsT (wave-private slice) ----
      {
        s16x8 bfr0 = *(const s16x8*)&wp[((l*4 + h)*32      + lm)*40 + q*8];
        s16x8 bfr1 = *(const s16x8*)&wp[((l*4 + h)*32 + 16 + lm)*40 + q*8];
        f32x4 z = {0.f,0.f,0.f,0.f};
        f32x4 d00 = MFMA16(af0, bfr0, z);   // nodes 0..15,  o = lm
        f32x4 d10 = MFMA16(af1, bfr0, z);   // nodes 16..31, o = lm
        f32x4 d01 = MFMA16(af0, bfr1, z);   // nodes 0..15,  o = 16+lm
        f32x4 d11 = MFMA16(af1, bfr1, z);   // nodes 16..31, o = 16+lm
        // poison s_dst (o=27) pad node cols >= 26
        d11[0] = pm01 ? -1e30f : d11[0];
        d11[1] = pm01 ? -1e30f : d11[1];
        d11[2] = pm23 ? -1e30f : d11[2];
        d11[3] = pm23 ? -1e30f : d11[3];
        const int rlo = lm*136 + b32 + q*4;
        { uint2 uu; uu.x = pack2(d00[0], d00[1]); uu.y = pack2(d00[2], d00[3]);
          *(uint2*)&hsT[rlo] = uu; }
        { uint2 uu; uu.x = pack2(d10[0], d10[1]); uu.y = pack2(d10[2], d10[3]);
          *(uint2*)&hsT[rlo + 16] = uu; }
        if (lm < 12){
          const int rhi = (16 + lm)*136 + b32 + q*4;
          { uint2 uu; uu.x = pack2(d01[0], d01[1]); uu.y = pack2(d01[2], d01[3]);
            *(uint2*)&hsT[rhi] = uu; }
          { uint2 uu; uu.x = pack2(d11[0], d11[1]); uu.y = pack2(d11[2], d11[3]);
            *(uint2*)&hsT[rhi + 16] = uu; }
        }
      }
      // ---- matmul2(h): softmax in-register (row-paired), PV accumulate ----
      {
        uint4 sdv = *(const uint4*)&hsT[27*136 + b32 + j0];
        // row-pair: component .x -> i = lm (nt=0), .y -> i = 16+lm (nt=1)
        f32x2 si;
        si.x = bf2f(hsT[26*136 + b32 + lm]);
        si.y = bf2f(hsT[26*136 + b32 + 16 + lm]);
        f32x2 p2[8]; f32x2 loc = {0.f, 0.f};
        #pragma unroll
        for (int jj = 0; jj < 8; ++jj){
          // lazy unpack (constant-folded per unrolled jj): keeps only the
          // 4-reg sdv live across the loop instead of an 8-reg sd2[]
          u32 word = (jj < 2) ? sdv.x : (jj < 4) ? sdv.y
                   : (jj < 6) ? sdv.z : sdv.w;
          float sdj = (jj & 1) ? bfhi(word) : bflo(word);
          f32x2 e  = si + sdj;                   // v_pk_add_f32
          f32x2 e2 = e * 0.2f;                   // v_pk_mul_f32
          f32x2 m;                               // leaky (log2 domain)
          m.x = fmaxf(e.x, e2.x);
          m.y = fmaxf(e.y, e2.y);
          f32x2 pv;
          pv.x = fexp2(m.x);                     // pad cols: exp2(-1e30)=0
          pv.y = fexp2(m.y);
          p2[jj] = pv;
          loc += pv;                             // v_pk_add_f32
        }
        float t0 = loc.x, t1 = loc.y;
        t0 += __shfl_xor(t0, 16); t0 += __shfl_xor(t0, 32);
        t1 += __shfl_xor(t1, 16); t1 += __shfl_xor(t1, 32);
        f32x2 rinv;
        rinv.x = __builtin_amdgcn_rcpf(t0);
        rinv.y = __builtin_amdgcn_rcpf(t1);
        #pragma unroll
        for (int jj = 0; jj < 8; ++jj) p2[jj] *= rinv;  // v_pk_mul_f32
        uint4 bu0 = { pack2(p2[0].x, p2[1].x), pack2(p2[2].x, p2[3].x),
                      pack2(p2[4].x, p2[5].x), pack2(p2[6].x, p2[7].x) };
        uint4 bu1 = { pack2(p2[0].y, p2[1].y), pack2(p2[2].y, p2[3].y),
                      pack2(p2[4].y, p2[5].y), pack2(p2[6].y, p2[7].y) };
        s16x8 bf0 = __builtin_bit_cast(s16x8, bu0);
        s16x8 bf1 = __builtin_bit_cast(s16x8, bu1);
        // am loads last: shortens their 16-reg live range to the MFMA cluster
        s16x8 am0 = *(const s16x8*)&hsT[ lm      *136 + b32 + j0];
        s16x8 am1 = *(const s16x8*)&hsT[(16+lmc)*136 + b32 + j0];
        acc00 = MFMA16(am0, bf0, acc00);
        acc10 = MFMA16(am1, bf0, acc10);
        acc01 = MFMA16(am0, bf1, acc01);
        acc11 = MFMA16(am1, bf1, acc11);
      }
    }
    // epilogue: heads pre-meaned (0.25 in wp), ELU, write next-layer xs
    #pragma unroll
    for (int nt = 0; nt < 2; ++nt){
      int i = nt*16 + lm;
      if (i < 26){
        int rowb = (b32 + i) << 5;
        #pragma unroll
        for (int mt = 0; mt < 2; ++mt){
          f32x4 a = (mt == 0) ? (nt == 0 ? acc00 : acc01)
                              : (nt == 0 ? acc10 : acc11);
          int f0 = mt*16 + q*4;
          float v0 = a[0], v1 = a[1], v2 = a[2], v3 = a[3];
          v0 = (v0 > 0.f) ? v0 : (fexp2(v0*L2E) - 1.f);
          v1 = (v1 > 0.f) ? v1 : (fexp2(v1*L2E) - 1.f);
          v2 = (v2 > 0.f) ? v2 : (fexp2(v2*L2E) - 1.f);
          v3 = (v3 > 0.f) ? v3 : (fexp2(v3*L2E) - 1.f);
          if (f0 <= 20){
            uint2 uu; uu.x = pack2(v0, v1); uu.y = pack2(v2, v3);
            *(uint2*)&xs[rowb + f0] = uu;
          } else if (f0 == 24){
            *(u32*)&xs[rowb + 24] = pack2(v0, v1);
          }
        }
      }
    }
    // no barrier: xs rows b32.. are wave-private
  }
  __syncthreads();   // tail store mixes batches within 64B chunks
  // store x_final into swizzled A-fragment layout, destination-linear:
  // each 16-thread group writes one contiguous 64B chunk (4 rows x 8 bf16).
  {
    const int mtile = b0 >> 4;
    const int lrow0 = b0 & 15;               // 0,4,8,12
    u16* dstb = xf + (size_t)mtile*22*64*8;
    for (int e = tid; e < 1408; e += 256){
      int chunk = e >> 4;                    // 0..87 = kc*4 + q16
      int u     = e & 15;                    // u32 slot within 64B chunk
      int kc = chunk >> 2, q16 = chunk & 3;
      int bb = u >> 2;                       // local batch 0..3
      int j2 = (u & 3) * 2;
      int k  = kc*32 + q16*8 + j2;           // flat feature (0..703, even)
      u32 v = 0;
      if (k < 676){ int n = k/26, f = k - n*26; v = *(const u32*)&xs[((bb*32 + n) << 5) + f]; }
      *(u32*)&dstb[((kc*64 + q16*16 + lrow0 + bb) << 3) + j2] = v;
    }
  }
}

// ---------------------------------------------------------------------------
// MLP: out = leaky(xf @ W1 + b1, 0.2) @ W2 + b2.  BM=32, grid 512 (2/CU,
// 8 waves/CU). Barrier-free, LDS-free K-loop with 2-stage register prefetch;
// all fragments coalesced (1KB/wave) from swizzled layouts. Fused W2 head.
// ---------------------------------------------------------------------------
__global__ __launch_bounds__(256, 2) void mlp_kernel(
    const u16* __restrict__ xf, const u16* __restrict__ w1t,
    const float* __restrict__ b1, const float* __restrict__ w2,
    const float* __restrict__ b2, float* __restrict__ out)
{
  __shared__ float b1s[256];
  __shared__ float w2s[256*3];
  __shared__ float part[4*32*3];

  const int tid  = threadIdx.x;
  const int w    = tid >> 6;
  const int lane = tid & 63;
  const int q    = lane >> 4;
  const int lm   = lane & 15;
  const int m0   = blockIdx.x * 32;
  const int mt0  = blockIdx.x * 2;         // 2 mtiles per block

  b1s[tid] = b1[tid];
  for (int e = tid; e < 768; e += 256) w2s[e] = w2[e];

  f32x4 acc[2][4];
  #pragma unroll
  for (int a = 0; a < 2; ++a)
    #pragma unroll
    for (int b = 0; b < 4; ++b) acc[a][b] = (f32x4){0.f,0.f,0.f,0.f};

  const u16* abase = xf  + ((size_t)mt0*22*64 + lane) * 8;
  const u16* bbase = w1t + (((size_t)w*4)*22*64 + lane) * 8;

  s16x8 af[2], bf[4], afn[2], bfn[4];
  #pragma unroll
  for (int mt = 0; mt < 2; ++mt) af[mt] = *(const s16x8*)(abase + (size_t)(mt*22)*64*8);
  #pragma unroll
  for (int nt = 0; nt < 4; ++nt) bf[nt] = *(const s16x8*)(bbase + (size_t)(nt*22)*64*8);

  #pragma unroll
  for (int kc = 0; kc < 22; ++kc){
    if (kc < 21){
      #pragma unroll
      for (int mt = 0; mt < 2; ++mt)
        afn[mt] = *(const s16x8*)(abase + (size_t)(mt*22 + kc + 1)*64*8);
      #pragma unroll
      for (int nt = 0; nt < 4; ++nt)
        bfn[nt] = *(const s16x8*)(bbase + (size_t)(nt*22 + kc + 1)*64*8);
    }
    #pragma unroll
    for (int mt = 0; mt < 2; ++mt)
      #pragma unroll
      for (int nt = 0; nt < 4; ++nt)
        acc[mt][nt] = MFMA16(af[mt], bf[nt], acc[mt][nt]);
    #pragma unroll
    for (int mt = 0; mt < 2; ++mt) af[mt] = afn[mt];
    #pragma unroll
    for (int nt = 0; nt < 4; ++nt) bf[nt] = bfn[nt];
  }

  // epilogue: +b1, leaky, @W2 partials, reduce over 16 lanes (cols)
  float b1l[4], w2l[4][3];
  #pragma unroll
  for (int nt = 0; nt < 4; ++nt){
    int col = w*64 + nt*16 + lm;
    b1l[nt] = b1s[col];
    w2l[nt][0] = w2s[col*3]; w2l[nt][1] = w2s[col*3+1]; w2l[nt][2] = w2s[col*3+2];
  }
  float po[2][4][3];
  #pragma unroll
  for (int mt = 0; mt < 2; ++mt)
    #pragma unroll
    for (int r = 0; r < 4; ++r){
      float s0 = 0.f, s1 = 0.f, s2 = 0.f;
      #pragma unroll
      for (int nt = 0; nt < 4; ++nt){
        float hv = acc[mt][nt][r] + b1l[nt];
        hv = (hv >= 0.f) ? hv : 0.2f*hv;
        s0 += hv*w2l[nt][0]; s1 += hv*w2l[nt][1]; s2 += hv*w2l[nt][2];
      }
      po[mt][r][0] = s0; po[mt][r][1] = s1; po[mt][r][2] = s2;
    }
  #pragma unroll
  for (int m = 1; m < 16; m <<= 1)
    #pragma unroll
    for (int mt = 0; mt < 2; ++mt)
      #pragma unroll
      for (int r = 0; r < 4; ++r)
        #pragma unroll
        for (int kk = 0; kk < 3; ++kk)
          po[mt][r][kk] += __shfl_xor(po[mt][r][kk], m);
  if (lm == 0){
    #pragma unroll
    for (int mt = 0; mt < 2; ++mt)
      #pragma unroll
      for (int r = 0; r < 4; ++r)
        #pragma unroll
        for (int kk = 0; kk < 3; ++kk)
          part[w*96 + (mt*16 + q*4 + r)*3 + kk] = po[mt][r][kk];
  }
  __syncthreads();
  if (tid < 96){
    int row = tid/3, kk = tid - row*3;
    float o = part[row*3 + kk] + part[96 + row*3 + kk]
            + part[192 + row*3 + kk] + part[288 + row*3 + kk] + b2[kk];
    out[(m0 + row)*3 + kk] = o;
  }
}

extern "C" void kernel_launch(void* const* d_in, const int* in_sizes, int n_in,
                              void* d_out, int out_size, void* d_ws, size_t ws_size,
                              hipStream_t stream)
{
  (void)in_sizes; (void)n_in; (void)out_size; (void)ws_size;
  const float* x     = (const float*)d_in[1];
  const float* W     = (const float*)d_in[2];
  const float* a_src = (const float*)d_in[3];
  const float* a_dst = (const float*)d_in[4];
  const float* W1    = (const float*)d_in[5];
  const float* b1    = (const float*)d_in[6];
  const float* W2    = (const float*)d_in[7];
  const float* b2    = (const float*)d_in[8];
  float* out = (float*)d_out;

  u16* xfinal = (u16*)d_ws;                    // [1024][22][64][8] bf16 (swz)
  u16* w1t    = xfinal + (size_t)16384*704;    // [16][22][64][8]   bf16 (swz)
  u16* wp     = w1t    + 256*704;              // [12][32][40]      bf16

  hipLaunchKernelGGL(prep_kernel, dim3(364),  dim3(256), 0, stream,
                     W, a_src, a_dst, W1, w1t, wp);
  hipLaunchKernelGGL(gat_kernel,  dim3(4096), dim3(256), 0, stream, x, wp, xfinal);
  hipLaunchKernelGGL(mlp_kernel,  dim3(512),  dim3(256), 0, stream,
                     xfinal, w1t, b1, W2, b2, out);
}

// Round 10
// 176.651 us; speedup vs baseline: 1.0239x; 1.0143x over previous
//
#include <hip/hip_runtime.h>

typedef __attribute__((ext_vector_type(8))) short s16x8;
typedef __attribute__((ext_vector_type(4))) float f32x4;
typedef __attribute__((ext_vector_type(2))) float f32x2;
typedef __attribute__((ext_vector_type(2))) __bf16 bf16x2;
typedef unsigned short u16;
typedef unsigned int   u32;

#define MFMA16(a,b,c) __builtin_amdgcn_mfma_f32_16x16x32_bf16((a),(b),(c),0,0,0)

__device__ __forceinline__ float bf2f(u16 u){
  u32 x = ((u32)u) << 16; float f; __builtin_memcpy(&f, &x, 4); return f;
}
__device__ __forceinline__ float bflo(u32 v){   // low bf16 of packed pair
  u32 x = v << 16; float f; __builtin_memcpy(&f, &x, 4); return f;
}
__device__ __forceinline__ float bfhi(u32 v){   // high bf16 of packed pair
  u32 x = v & 0xFFFF0000u; float f; __builtin_memcpy(&f, &x, 4); return f;
}
__device__ __forceinline__ u16 f2bf(float f){
  u32 x; __builtin_memcpy(&x, &f, 4);
  x += 0x7FFFu + ((x >> 16) & 1u);   // round-to-nearest-even
  return (u16)(x >> 16);
}
// pack two f32 -> packed bf16 pair (a in low 16, b in high 16), RNE.
// gfx950: clang lowers __bf16 casts to the native convert; this is the
// sanctioned fast path (round 2: gat 117->94us from this alone).
__device__ __forceinline__ u32 pack2(float a, float b){
  bf16x2 h = { (__bf16)a, (__bf16)b };
  return __builtin_bit_cast(u32, h);
}
#if defined(__has_builtin) && __has_builtin(__builtin_amdgcn_exp2f)
__device__ __forceinline__ float fexp2(float x){ return __builtin_amdgcn_exp2f(x); }
#else
extern "C" __device__ float __ocml_native_exp2_f32(float);
__device__ __forceinline__ float fexp2(float x){ return __ocml_native_exp2_f32(x); }
#endif

// Layouts:
// xf_swz : [mtile=1024][kc=22][lane=64][8]  A[m=lane&15][k=kc*32+(lane>>4)*8+j]
// w1_swz : [ntile=16]  [kc=22][lane=64][8]  B[k=...][n=ntile*16+(lane&15)]
// wp[l*4+h] : [32 rows o][stride 40 f];
//   rows 0..25 : 0.25 * W^T          (0.25 head-mean folded in — exact, pow2)
//   row  26    : log2e * (W @ a_src)  row 27 : log2e * (W @ a_dst)
//   rows 28..31 / cols >= 26 : 0
// gat LDS (pad-32 nodes, WAVE-PRIVATE per local batch w):
//   xs [128 rows = w*32+n][stride 32]; hsT[28 rows o][stride 136] SINGLE-HEAD
//   (heads interleaved matmul1(h) -> matmul2(h); wave-private, zero barriers).
//   FINAL config notes (measured matrix, rounds 4-9):
//     (256,8) cap 64              -> heavy spill, gat 110us
//     (256,6) cap 84 (± diet)     -> mild spill, gat 85 / 83.7
//     (256,5) cap 102 + diet      -> CLEAN (VGPR 40, WRITE 22528), gat 82.8
//     r7 early-read head pipeline -> +8 VGPR, occ 45.6%, gat 84.7 (reverted)
//   (256,5)+diet is the register-constrained optimum: more occupancy or more
//   intra-wave pipelining both cost regs and lose more than they gain.
// ---------------------------------------------------------------------------
// prep: blocks 0..351: W1 -> w1_swz; blocks 352..363: wp for lh = blk-352.
// ---------------------------------------------------------------------------
__global__ __launch_bounds__(256) void prep_kernel(
    const float* __restrict__ W, const float* __restrict__ a_src,
    const float* __restrict__ a_dst, const float* __restrict__ W1,
    u16* __restrict__ w1t, u16* __restrict__ wp)
{
  const int t = threadIdx.x;
  if (blockIdx.x < 352){
    const int k = blockIdx.x * 2;            // 0..702 even
    const int n = t;
    float v0 = 0.f, v1 = 0.f;
    if (k < 676)     v0 = W1[(size_t)k*256 + n];
    if (k + 1 < 676) v1 = W1[(size_t)(k+1)*256 + n];
    const int ntile = n >> 4, lm = n & 15;
    const int kc = k >> 5, q16 = (k >> 3) & 3, j = k & 7;
    u16* dst = w1t + ((((size_t)ntile*22 + kc)*64 + q16*16 + lm) << 3) + j;
    *(u32*)dst = pack2(v0, v1);
  } else {
    const int lh = blockIdx.x - 352;         // 0..11 = l*4+h
    const float* Wlh = W + lh*676;           // [f][o]
    u16* dst = wp + lh*32*40;
    for (int e = t; e < 1280; e += 256) dst[e] = 0;
    __syncthreads();
    for (int e = t; e < 676; e += 256){      // value rows: 0.25*W^T
      int f = e/26, o = e%26;
      dst[o*40 + f] = f2bf(0.25f * Wlh[f*26 + o]);
    }
    if (t < 52){                             // score rows: log2e * (W@a)
      int sel = t/26, f = t%26;
      const float* av = (sel ? a_dst : a_src) + lh*26;
      float acc = 0.f;
      #pragma unroll
      for (int o = 0; o < 26; ++o) acc += Wlh[f*26 + o]*av[o];
      dst[(26 + sel)*40 + f] = f2bf(1.4426950408889634f * acc);
    }
  }
}

// ---------------------------------------------------------------------------
// GAT kernel: 3 fused layers, barrier-free layer loop (wave = batch for both
// matmuls; xs/hsT regions wave-private). One block = 4 batches, 256 threads,
// ~5 blocks/CU (single-head hsT, no-spill register budget). Heads interleaved
// per-layer: matmul1(h) -> hsT -> softmax+PV(h); write->read hazard is
// wave-local lgkmcnt, hidden by multi-wave occupancy. Single __syncthreads
// before the xf tail store.
// ---------------------------------------------------------------------------
__global__ __launch_bounds__(256, 5) void gat_kernel(
    const float* __restrict__ x, const u16* __restrict__ wp,
    u16* __restrict__ xf)
{
  __shared__ __align__(16) u16 xs [128*32];
  __shared__ __align__(16) u16 hsT[28*136];

  const int tid  = threadIdx.x;
  const int w    = tid >> 6;                 // wave = local batch
  const int lane = tid & 63;
  const int q    = lane >> 4;
  const int lm   = lane & 15;
  const int lmc  = (lm < 11) ? lm : 11;      // clamp for am1 row reads
  const int b0   = blockIdx.x * 4;
  const int b32  = w*32;
  const float L2E = 1.4426950408889634f;

  // poison masks for d11 (o = 16+lm = 27, node col 16+q*4+r >= 26)
  const bool pm01 = (lm == 11) && (q == 3);  // regs 0,1
  const bool pm23 = (lm == 11) && (q >= 2);  // regs 2,3

  // wave-private xs zero (own 32 rows = 512 u32), then stage own batch
  for (int e = lane; e < 512; e += 64) ((u32*)xs)[w*512 + e] = 0;
  for (int pp = lane; pp < 338; pp += 64){
    int n = pp/13, p = pp%13;
    float2 v = *(const float2*)&x[(size_t)(b0 + w)*676 + n*26 + 2*p];
    *(u32*)&xs[((b32 + n) << 5) + 2*p] = pack2(v.x, v.y);
  }

  for (int l = 0; l < 3; ++l){
    s16x8 af0 = *(const s16x8*)&xs[((b32      + lm) << 5) + q*8];
    s16x8 af1 = *(const s16x8*)&xs[((b32 + 16 + lm) << 5) + q*8];
    f32x4 acc00 = {0,0,0,0}, acc01 = acc00, acc10 = acc00, acc11 = acc00;
    const int j0 = q*8;
    #pragma unroll
    for (int h = 0; h < 4; ++h){
      // ---- matmul1(h): h_aug = x @ W_aug -> hsT (wave-private slice) ----
      {
        s16x8 bfr0 = *(const s16x8*)&wp[((l*4 + h)*32      + lm)*40 + q*8];
        s16x8 bfr1 = *(const s16x8*)&wp[((l*4 + h)*32 + 16 + lm)*40 + q*8];
        f32x4 z = {0.f,0.f,0.f,0.f};
        f32x4 d00 = MFMA16(af0, bfr0, z);   // nodes 0..15,  o = lm
        f32x4 d10 = MFMA16(af1, bfr0, z);   // nodes 16..31, o = lm
        f32x4 d01 = MFMA16(af0, bfr1, z);   // nodes 0..15,  o = 16+lm
        f32x4 d11 = MFMA16(af1, bfr1, z);   // nodes 16..31, o = 16+lm
        // poison s_dst (o=27) pad node cols >= 26
        d11[0] = pm01 ? -1e30f : d11[0];
        d11[1] = pm01 ? -1e30f : d11[1];
        d11[2] = pm23 ? -1e30f : d11[2];
        d11[3] = pm23 ? -1e30f : d11[3];
        const int rlo = lm*136 + b32 + q*4;
        { uint2 uu; uu.x = pack2(d00[0], d00[1]); uu.y = pack2(d00[2], d00[3]);
          *(uint2*)&hsT[rlo] = uu; }
        { uint2 uu; uu.x = pack2(d10[0], d10[1]); uu.y = pack2(d10[2], d10[3]);
          *(uint2*)&hsT[rlo + 16] = uu; }
        if (lm < 12){
          const int rhi = (16 + lm)*136 + b32 + q*4;
          { uint2 uu; uu.x = pack2(d01[0], d01[1]); uu.y = pack2(d01[2], d01[3]);
            *(uint2*)&hsT[rhi] = uu; }
          { uint2 uu; uu.x = pack2(d11[0], d11[1]); uu.y = pack2(d11[2], d11[3]);
            *(uint2*)&hsT[rhi + 16] = uu; }
        }
      }
      // ---- matmul2(h): softmax in-register (row-paired), PV accumulate ----
      {
        uint4 sdv = *(const uint4*)&hsT[27*136 + b32 + j0];
        // row-pair: component .x -> i = lm (nt=0), .y -> i = 16+lm (nt=1)
        f32x2 si;
        si.x = bf2f(hsT[26*136 + b32 + lm]);
        si.y = bf2f(hsT[26*136 + b32 + 16 + lm]);
        f32x2 p2[8]; f32x2 loc = {0.f, 0.f};
        #pragma unroll
        for (int jj = 0; jj < 8; ++jj){
          // lazy unpack (constant-folded per unrolled jj): keeps only the
          // 4-reg sdv live across the loop instead of an 8-reg sd2[]
          u32 word = (jj < 2) ? sdv.x : (jj < 4) ? sdv.y
                   : (jj < 6) ? sdv.z : sdv.w;
          float sdj = (jj & 1) ? bfhi(word) : bflo(word);
          f32x2 e  = si + sdj;                   // v_pk_add_f32
          f32x2 e2 = e * 0.2f;                   // v_pk_mul_f32
          f32x2 m;                               // leaky (log2 domain)
          m.x = fmaxf(e.x, e2.x);
          m.y = fmaxf(e.y, e2.y);
          f32x2 pv;
          pv.x = fexp2(m.x);                     // pad cols: exp2(-1e30)=0
          pv.y = fexp2(m.y);
          p2[jj] = pv;
          loc += pv;                             // v_pk_add_f32
        }
        float t0 = loc.x, t1 = loc.y;
        t0 += __shfl_xor(t0, 16); t0 += __shfl_xor(t0, 32);
        t1 += __shfl_xor(t1, 16); t1 += __shfl_xor(t1, 32);
        f32x2 rinv;
        rinv.x = __builtin_amdgcn_rcpf(t0);
        rinv.y = __builtin_amdgcn_rcpf(t1);
        #pragma unroll
        for (int jj = 0; jj < 8; ++jj) p2[jj] *= rinv;  // v_pk_mul_f32
        uint4 bu0 = { pack2(p2[0].x, p2[1].x), pack2(p2[2].x, p2[3].x),
                      pack2(p2[4].x, p2[5].x), pack2(p2[6].x, p2[7].x) };
        uint4 bu1 = { pack2(p2[0].y, p2[1].y), pack2(p2[2].y, p2[3].y),
                      pack2(p2[4].y, p2[5].y), pack2(p2[6].y, p2[7].y) };
        s16x8 bf0 = __builtin_bit_cast(s16x8, bu0);
        s16x8 bf1 = __builtin_bit_cast(s16x8, bu1);
        // am loads last: shortens their 16-reg live range to the MFMA cluster
        s16x8 am0 = *(const s16x8*)&hsT[ lm      *136 + b32 + j0];
        s16x8 am1 = *(const s16x8*)&hsT[(16+lmc)*136 + b32 + j0];
        acc00 = MFMA16(am0, bf0, acc00);
        acc10 = MFMA16(am1, bf0, acc10);
        acc01 = MFMA16(am0, bf1, acc01);
        acc11 = MFMA16(am1, bf1, acc11);
      }
    }
    // epilogue: heads pre-meaned (0.25 in wp), ELU, write next-layer xs
    #pragma unroll
    for (int nt = 0; nt < 2; ++nt){
      int i = nt*16 + lm;
      if (i < 26){
        int rowb = (b32 + i) << 5;
        #pragma unroll
        for (int mt = 0; mt < 2; ++mt){
          f32x4 a = (mt == 0) ? (nt == 0 ? acc00 : acc01)
                              : (nt == 0 ? acc10 : acc11);
          int f0 = mt*16 + q*4;
          float v0 = a[0], v1 = a[1], v2 = a[2], v3 = a[3];
          v0 = (v0 > 0.f) ? v0 : (fexp2(v0*L2E) - 1.f);
          v1 = (v1 > 0.f) ? v1 : (fexp2(v1*L2E) - 1.f);
          v2 = (v2 > 0.f) ? v2 : (fexp2(v2*L2E) - 1.f);
          v3 = (v3 > 0.f) ? v3 : (fexp2(v3*L2E) - 1.f);
          if (f0 <= 20){
            uint2 uu; uu.x = pack2(v0, v1); uu.y = pack2(v2, v3);
            *(uint2*)&xs[rowb + f0] = uu;
          } else if (f0 == 24){
            *(u32*)&xs[rowb + 24] = pack2(v0, v1);
          }
        }
      }
    }
    // no barrier: xs rows b32.. are wave-private
  }
  __syncthreads();   // tail store mixes batches within 64B chunks
  // store x_final into swizzled A-fragment layout, destination-linear:
  // each 16-thread group writes one contiguous 64B chunk (4 rows x 8 bf16).
  {
    const int mtile = b0 >> 4;
    const int lrow0 = b0 & 15;               // 0,4,8,12
    u16* dstb = xf + (size_t)mtile*22*64*8;
    for (int e = tid; e < 1408; e += 256){
      int chunk = e >> 4;                    // 0..87 = kc*4 + q16
      int u     = e & 15;                    // u32 slot within 64B chunk
      int kc = chunk >> 2, q16 = chunk & 3;
      int bb = u >> 2;                       // local batch 0..3
      int j2 = (u & 3) * 2;
      int k  = kc*32 + q16*8 + j2;           // flat feature (0..703, even)
      u32 v = 0;
      if (k < 676){ int n = k/26, f = k - n*26; v = *(const u32*)&xs[((bb*32 + n) << 5) + f]; }
      *(u32*)&dstb[((kc*64 + q16*16 + lrow0 + bb) << 3) + j2] = v;
    }
  }
}

// ---------------------------------------------------------------------------
// MLP: out = leaky(xf @ W1 + b1, 0.2) @ W2 + b2.  BM=32, grid 512 (2/CU,
// 8 waves/CU). Barrier-free, LDS-free K-loop with 2-stage register prefetch;
// all fragments coalesced (1KB/wave) from swizzled layouts. Fused W2 head.
// ---------------------------------------------------------------------------
__global__ __launch_bounds__(256, 2) void mlp_kernel(
    const u16* __restrict__ xf, const u16* __restrict__ w1t,
    const float* __restrict__ b1, const float* __restrict__ w2,
    const float* __restrict__ b2, float* __restrict__ out)
{
  __shared__ float b1s[256];
  __shared__ float w2s[256*3];
  __shared__ float part[4*32*3];

  const int tid  = threadIdx.x;
  const int w    = tid >> 6;
  const int lane = tid & 63;
  const int q    = lane >> 4;
  const int lm   = lane & 15;
  const int m0   = blockIdx.x * 32;
  const int mt0  = blockIdx.x * 2;         // 2 mtiles per block

  b1s[tid] = b1[tid];
  for (int e = tid; e < 768; e += 256) w2s[e] = w2[e];

  f32x4 acc[2][4];
  #pragma unroll
  for (int a = 0; a < 2; ++a)
    #pragma unroll
    for (int b = 0; b < 4; ++b) acc[a][b] = (f32x4){0.f,0.f,0.f,0.f};

  const u16* abase = xf  + ((size_t)mt0*22*64 + lane) * 8;
  const u16* bbase = w1t + (((size_t)w*4)*22*64 + lane) * 8;

  s16x8 af[2], bf[4], afn[2], bfn[4];
  #pragma unroll
  for (int mt = 0; mt < 2; ++mt) af[mt] = *(const s16x8*)(abase + (size_t)(mt*22)*64*8);
  #pragma unroll
  for (int nt = 0; nt < 4; ++nt) bf[nt] = *(const s16x8*)(bbase + (size_t)(nt*22)*64*8);

  #pragma unroll
  for (int kc = 0; kc < 22; ++kc){
    if (kc < 21){
      #pragma unroll
      for (int mt = 0; mt < 2; ++mt)
        afn[mt] = *(const s16x8*)(abase + (size_t)(mt*22 + kc + 1)*64*8);
      #pragma unroll
      for (int nt = 0; nt < 4; ++nt)
        bfn[nt] = *(const s16x8*)(bbase + (size_t)(nt*22 + kc + 1)*64*8);
    }
    #pragma unroll
    for (int mt = 0; mt < 2; ++mt)
      #pragma unroll
      for (int nt = 0; nt < 4; ++nt)
        acc[mt][nt] = MFMA16(af[mt], bf[nt], acc[mt][nt]);
    #pragma unroll
    for (int mt = 0; mt < 2; ++mt) af[mt] = afn[mt];
    #pragma unroll
    for (int nt = 0; nt < 4; ++nt) bf[nt] = bfn[nt];
  }

  // epilogue: +b1, leaky, @W2 partials, reduce over 16 lanes (cols)
  float b1l[4], w2l[4][3];
  #pragma unroll
  for (int nt = 0; nt < 4; ++nt){
    int col = w*64 + nt*16 + lm;
    b1l[nt] = b1s[col];
    w2l[nt][0] = w2s[col*3]; w2l[nt][1] = w2s[col*3+1]; w2l[nt][2] = w2s[col*3+2];
  }
  float po[2][4][3];
  #pragma unroll
  for (int mt = 0; mt < 2; ++mt)
    #pragma unroll
    for (int r = 0; r < 4; ++r){
      float s0 = 0.f, s1 = 0.f, s2 = 0.f;
      #pragma unroll
      for (int nt = 0; nt < 4; ++nt){
        float hv = acc[mt][nt][r] + b1l[nt];
        hv = (hv >= 0.f) ? hv : 0.2f*hv;
        s0 += hv*w2l[nt][0]; s1 += hv*w2l[nt][1]; s2 += hv*w2l[nt][2];
      }
      po[mt][r][0] = s0; po[mt][r][1] = s1; po[mt][r][2] = s2;
    }
  #pragma unroll
  for (int m = 1; m < 16; m <<= 1)
    #pragma unroll
    for (int mt = 0; mt < 2; ++mt)
      #pragma unroll
      for (int r = 0; r < 4; ++r)
        #pragma unroll
        for (int kk = 0; kk < 3; ++kk)
          po[mt][r][kk] += __shfl_xor(po[mt][r][kk], m);
  if (lm == 0){
    #pragma unroll
    for (int mt = 0; mt < 2; ++mt)
      #pragma unroll
      for (int r = 0; r < 4; ++r)
        #pragma unroll
        for (int kk = 0; kk < 3; ++kk)
          part[w*96 + (mt*16 + q*4 + r)*3 + kk] = po[mt][r][kk];
  }
  __syncthreads();
  if (tid < 96){
    int row = tid/3, kk = tid - row*3;
    float o = part[row*3 + kk] + part[96 + row*3 + kk]
            + part[192 + row*3 + kk] + part[288 + row*3 + kk] + b2[kk];
    out[(m0 + row)*3 + kk] = o;
  }
}

extern "C" void kernel_launch(void* const* d_in, const int* in_sizes, int n_in,
                              void* d_out, int out_size, void* d_ws, size_t ws_size,
                              hipStream_t stream)
{
  (void)in_sizes; (void)n_in; (void)out_size; (void)ws_size;
  const float* x     = (const float*)d_in[1];
  const float* W     = (const float*)d_in[2];
  const float* a_src = (const float*)d_in[3];
  const float* a_dst = (const float*)d_in[4];
  const float* W1    = (const float*)d_in[5];
  const float* b1    = (const float*)d_in[6];
  const float* W2    = (const float*)d_in[7];
  const float* b2    = (const float*)d_in[8];
  float* out = (float*)d_out;

  u16* xfinal = (u16*)d_ws;                    // [1024][22][64][8] bf16 (swz)
  u16* w1t    = xfinal + (size_t)16384*704;    // [16][22][64][8]   bf16 (swz)
  u16* wp     = w1t    + 256*704;              // [12][32][40]      bf16

  hipLaunchKernelGGL(prep_kernel, dim3(364),  dim3(256), 0, stream,
                     W, a_src, a_dst, W1, w1t, wp);
  hipLaunchKernelGGL(gat_kernel,  dim3(4096), dim3(256), 0, stream, x, wp, xfinal);
  hipLaunchKernelGGL(mlp_kernel,  dim3(512),  dim3(256), 0, stream,
                     xfinal, w1t, b1, W2, b2, out);
}